// Round 22
// baseline (63.055 us; speedup 1.0000x reference)
//
#include <hip/hip_runtime.h>
#include <hip/hip_bf16.h>

// z = segment_sum( (x @ W_fc^T)[col], row )  -- alpha==1 (softmax over singleton dim)
// Round 22: splitB 128->256 (TLP is the split's proven lever: r20->r21 A/B).
// 16B packed runs on 3.2MB bucket array -> ~+4MB writeback, cheap vs TLP gain.
// Pipeline: zero -> fc||split -> gatherz2

#define BSHIFT 6
#define BNODES 64          // nodes per bucket
#define CAPB 2048          // u32 entries per bucket list (avg ~1024)
#define CAP 48             // slots per node (P(deg>48 | Poisson(16)) ~ 1e-11)
#define OVFCAP 128         // in-LDS overflow list (never used in practice)
#define SPILLCAP 65536
#define MAXNB 1024

__device__ inline unsigned short f2bf(float f) {
    __hip_bfloat16 h = __float2bfloat16(f);
    return *reinterpret_cast<unsigned short*>(&h);
}

// ---------- zero: cursors (stride-16) + spillcnt ----------
__global__ void zero_kernel(int* __restrict__ a, int n) {
    int i = blockIdx.x * blockDim.x + threadIdx.x;
    int s = gridDim.x * blockDim.x;
    for (; i < n; i += s) a[i] = 0;
}

// ---------- K1: blocks [0,splitB) coarse-split edges into packed bucket lists; rest fc ----------
__global__ __launch_bounds__(256) void fc_split(
        const float* __restrict__ x, const float* __restrict__ Wfc,
        unsigned short* __restrict__ y, int N,
        const int* __restrict__ eidx, unsigned* __restrict__ buckets,
        int* __restrict__ cursor, int* __restrict__ spillcnt, int* __restrict__ spill,
        int E, int NB, int splitB) {
    if ((int)blockIdx.x < splitB) {
        __shared__ int hist[MAXNB];
        __shared__ int bases[MAXNB];
        int chunk = (E + splitB - 1) / splitB;       // ~3125 -> 4 packed entries/run
        int e0 = (int)blockIdx.x * chunk;
        int e1 = e0 + chunk; if (e1 > E) e1 = E;
        for (int i = threadIdx.x; i < NB; i += 256) hist[i] = 0;
        __syncthreads();
        for (int e = e0 + threadIdx.x; e < e1; e += 256)
            atomicAdd(&hist[eidx[e] >> BSHIFT], 1);      // LDS hist, pass 1
        __syncthreads();
        for (int b = threadIdx.x; b < NB; b += 256) {
            int c = hist[b];
            bases[b] = c ? atomicAdd(&cursor[b * 16], c) : 0;  // 1 global atomic/bucket
            hist[b] = 0;                                 // reuse as rank counter
        }
        __syncthreads();
        for (int e = e0 + threadIdx.x; e < e1; e += 256) {   // pass 2 (L2-hot reread)
            int r = eidx[e];
            int c = eidx[E + e];
            int b = r >> BSHIFT;
            int pos = bases[b] + atomicAdd(&hist[b], 1);
            if (pos < CAPB) {
                buckets[(size_t)b * CAPB + pos] =
                    ((unsigned)(r & (BNODES - 1)) << 16) | (unsigned)c;
            } else {
                int q = atomicAdd(spillcnt, 1);
                if (q < SPILLCAP) { spill[2 * q] = r; spill[2 * q + 1] = c; }
            }
        }
    } else {
        // ---- fc: 16 rows/block (4/thread), bf16 out; float4 LDS reads ----
        __shared__ float sW[64][68];   // stride 272B: 16B-aligned rows
        __shared__ float sX[16][64];
        for (int i = threadIdx.x; i < 4096; i += 256) sW[i >> 6][i & 63] = Wfc[i];
        int row0 = ((int)blockIdx.x - splitB) << 4;
        for (int i = threadIdx.x; i < 1024; i += 256) {
            int r = i >> 6, k = i & 63, gr = row0 + r;
            sX[r][k] = (gr < N) ? x[(size_t)gr * 64 + k] : 0.f;
        }
        __syncthreads();
        int co = threadIdx.x & 63;
        int rq = threadIdx.x >> 6;
        const float4* wrow = reinterpret_cast<const float4*>(&sW[co][0]);
        const float4* xr0  = reinterpret_cast<const float4*>(&sX[4 * rq + 0][0]);
        const float4* xr1  = reinterpret_cast<const float4*>(&sX[4 * rq + 1][0]);
        const float4* xr2  = reinterpret_cast<const float4*>(&sX[4 * rq + 2][0]);
        const float4* xr3  = reinterpret_cast<const float4*>(&sX[4 * rq + 3][0]);
        float a0 = 0, a1 = 0, a2 = 0, a3 = 0;
#pragma unroll
        for (int m = 0; m < 16; ++m) {
            float4 w  = wrow[m];
            float4 v0 = xr0[m], v1 = xr1[m], v2 = xr2[m], v3 = xr3[m];
            a0 = fmaf(w.x, v0.x, fmaf(w.y, v0.y, fmaf(w.z, v0.z, fmaf(w.w, v0.w, a0))));
            a1 = fmaf(w.x, v1.x, fmaf(w.y, v1.y, fmaf(w.z, v1.z, fmaf(w.w, v1.w, a1))));
            a2 = fmaf(w.x, v2.x, fmaf(w.y, v2.y, fmaf(w.z, v2.z, fmaf(w.w, v2.w, a2))));
            a3 = fmaf(w.x, v3.x, fmaf(w.y, v3.y, fmaf(w.z, v3.z, fmaf(w.w, v3.w, a3))));
        }
        int g = row0 + 4 * rq;
        if (g + 3 < N) {
            y[(size_t)(g + 0) * 64 + co] = f2bf(a0);
            y[(size_t)(g + 1) * 64 + co] = f2bf(a1);
            y[(size_t)(g + 2) * 64 + co] = f2bf(a2);
            y[(size_t)(g + 3) * 64 + co] = f2bf(a3);
        } else {
            if (g + 0 < N) y[(size_t)(g + 0) * 64 + co] = f2bf(a0);
            if (g + 1 < N) y[(size_t)(g + 1) * 64 + co] = f2bf(a1);
            if (g + 2 < N) y[(size_t)(g + 2) * 64 + co] = f2bf(a2);
        }
    }
}

// ---------- K2: per-bucket block: LDS slot build (+spill ingest) + per-node ILP gather ----------
__device__ inline void acc_bf8(const uint2* yb, int c, int ch4,
                               float& r0, float& r1, float& r2, float& r3) {
    uint2 u = yb[(size_t)c * 16 + ch4];             // 8 B/lane, 128 B per 16-lane group
    r0 += __uint_as_float(u.x << 16);
    r1 += __uint_as_float(u.x & 0xffff0000u);
    r2 += __uint_as_float(u.y << 16);
    r3 += __uint_as_float(u.y & 0xffff0000u);
}
__global__ __launch_bounds__(512) void gatherz2(
        const unsigned* __restrict__ buckets, const int* __restrict__ cursor,
        const uint2* __restrict__ yb2, float4* __restrict__ z4, int N,
        const int* __restrict__ spillcnt, const int* __restrict__ spill) {
    __shared__ int cntL[BNODES];            // 256 B
    __shared__ int slotsL[BNODES * CAP];    // 12 KB
    __shared__ int ovfN[OVFCAP], ovfC[OVFCAP], ovfn_sh;
    int b  = (int)blockIdx.x;
    int lo = b << BSHIFT;
    for (int i = threadIdx.x; i < BNODES; i += 512) cntL[i] = 0;
    if (threadIdx.x == 0) ovfn_sh = 0;
    __syncthreads();
    int ecnt = cursor[b * 16]; if (ecnt > CAPB) ecnt = CAPB;
    const unsigned* blist = buckets + (size_t)b * CAPB;
    const uint2* blist2 = (const uint2*)blist;
    int nPairs = ecnt >> 1;
    for (int p = threadIdx.x; p < nPairs; p += 512) {   // coalesced 8B = 2 entries
        uint2 ee = blist2[p];
#pragma unroll
        for (int h = 0; h < 2; ++h) {
            unsigned e = h ? ee.y : ee.x;
            int n = (int)(e >> 16);
            int c = (int)(e & 0xffffu);
            int slot = atomicAdd(&cntL[n], 1);
            if (slot < CAP) slotsL[n * CAP + slot] = c;
            else { int q = atomicAdd(&ovfn_sh, 1);
                   if (q < OVFCAP) { ovfN[q] = n; ovfC[q] = c; } }
        }
    }
    if ((ecnt & 1) && threadIdx.x == 0) {               // tail entry
        unsigned e = blist[ecnt - 1];
        int n = (int)(e >> 16), c = (int)(e & 0xffffu);
        int slot = atomicAdd(&cntL[n], 1);
        if (slot < CAP) slotsL[n * CAP + slot] = c;
        else { int q = atomicAdd(&ovfn_sh, 1);
               if (q < OVFCAP) { ovfN[q] = n; ovfC[q] = c; } }
    }
    int sc = *spillcnt;                                  // fc_split CAPB overflow (0)
    if (sc > SPILLCAP) sc = SPILLCAP;
    for (int i = threadIdx.x; i < sc; i += 512) {
        int r = spill[2 * i];
        if ((r >> BSHIFT) == b) {
            int n = r & (BNODES - 1), c = spill[2 * i + 1];
            int slot = atomicAdd(&cntL[n], 1);
            if (slot < CAP) slotsL[n * CAP + slot] = c;
            else { int q = atomicAdd(&ovfn_sh, 1);
                   if (q < OVFCAP) { ovfN[q] = n; ovfC[q] = c; } }
        }
    }
    __syncthreads();
    int on = ovfn_sh; if (on > OVFCAP) on = OVFCAP;
    int lane = threadIdx.x & 63;
    int wv   = threadIdx.x >> 6;                       // 8 waves
    int sub  = lane >> 4;                              // edge slot within group-of-4
    int ch4  = lane & 15;                              // 4-channel group
    for (int n = wv; n < BNODES; n += 8) {
        int node = lo + n;
        if (node >= N) break;                          // monotonic per wave
        int deg = cntL[n]; if (deg > CAP) deg = CAP;
        const int* srow = &slotsL[n * CAP];
        float A0=0,A1=0,A2=0,A3=0, B0=0,B1=0,B2=0,B3=0,
              C0=0,C1=0,C2=0,C3=0, D0=0,D1=0,D2=0,D3=0;
        for (int j = 0; j < deg; j += 16) {
            int j0 = j + sub, j1 = j + 4 + sub, j2 = j + 8 + sub, j3 = j + 12 + sub;
            int c0 = (j0 < deg) ? srow[j0] : -1;       // LDS broadcast per 16-lane group
            int c1 = (j1 < deg) ? srow[j1] : -1;
            int c2 = (j2 < deg) ? srow[j2] : -1;
            int c3 = (j3 < deg) ? srow[j3] : -1;
            if (c0 >= 0) acc_bf8(yb2, c0, ch4, A0, A1, A2, A3);
            if (c1 >= 0) acc_bf8(yb2, c1, ch4, B0, B1, B2, B3);
            if (c2 >= 0) acc_bf8(yb2, c2, ch4, C0, C1, C2, C3);
            if (c3 >= 0) acc_bf8(yb2, c3, ch4, D0, D1, D2, D3);
        }
        for (int k = 0; k < on; ++k)                    // normally on == 0
            if (ovfN[k] == n && sub == 0)
                acc_bf8(yb2, ovfC[k], ch4, A0, A1, A2, A3);
        float r0 = (A0 + B0) + (C0 + D0);
        float r1 = (A1 + B1) + (C1 + D1);
        float r2 = (A2 + B2) + (C2 + D2);
        float r3 = (A3 + B3) + (C3 + D3);
        r0 += __shfl_xor(r0, 16, 64); r0 += __shfl_xor(r0, 32, 64);
        r1 += __shfl_xor(r1, 16, 64); r1 += __shfl_xor(r1, 32, 64);
        r2 += __shfl_xor(r2, 16, 64); r2 += __shfl_xor(r2, 32, 64);
        r3 += __shfl_xor(r3, 16, 64); r3 += __shfl_xor(r3, 32, 64);
        if (lane < 16)
            z4[(size_t)node * 16 + ch4] = make_float4(r0, r1, r2, r3);
    }
}

// ---------- fallback (ws too small or N too big): fc f32 + atomic scatter ----------
__global__ void fc_kernel(const float* __restrict__ x, const float* __restrict__ Wfc,
                          float* __restrict__ y, int N) {
    __shared__ float sW[64][65];
    __shared__ float sX[4][64];
    for (int i = threadIdx.x; i < 64 * 64; i += 256) sW[i >> 6][i & 63] = Wfc[i];
    int r = threadIdx.x >> 6, co = threadIdx.x & 63;
    int gRow = (blockIdx.x << 2) + r;
    sX[r][co] = (gRow < N) ? x[gRow * 64 + co] : 0.f;
    __syncthreads();
    if (gRow >= N) return;
    float acc = 0.f;
#pragma unroll
    for (int k = 0; k < 64; ++k) acc = fmaf(sX[r][k], sW[co][k], acc);
    y[gRow * 64 + co] = acc;
}
__global__ void scatter_kernel(const int* __restrict__ eidx, const float* __restrict__ y,
                               float* __restrict__ z, int E) {
    int lane = threadIdx.x & 63;
    int g  = (int)((blockIdx.x * blockDim.x + threadIdx.x) >> 6);
    int nG = (int)((gridDim.x * blockDim.x) >> 6);
    for (int e = g; e < E; e += nG) {
        int r = eidx[e], c = eidx[E + e];
        atomicAdd(&z[r * 64 + lane], y[c * 64 + lane]);
    }
}

extern "C" void kernel_launch(void* const* d_in, const int* in_sizes, int n_in,
                              void* d_out, int out_size, void* d_ws, size_t ws_size,
                              hipStream_t stream) {
    const float* x    = (const float*)d_in[0];
    const int*   eidx = (const int*)d_in[1];
    const float* Wfc  = (const float*)d_in[3];   // d_in[2,4,5] unused (alpha==1)
    float*       z    = (float*)d_out;

    int N = in_sizes[0] / 64;
    int E = in_sizes[1] / 2;
    int NB = (N + BNODES - 1) >> BSHIFT;         // 64-node buckets

    // workspace: cursor[NB*16] | spillcnt | spill | buckets(u32) | yb
    char* w = (char*)d_ws;
    size_t off = 0;
    int* cursor   = (int*)(w + off); off += (size_t)NB * 16 * sizeof(int);
    int* spillcnt = (int*)(w + off); off += sizeof(int);
    off = (off + 255) & ~(size_t)255;
    int* spill    = (int*)(w + off); off += (size_t)2 * SPILLCAP * sizeof(int);
    off = (off + 255) & ~(size_t)255;
    unsigned* buckets = (unsigned*)(w + off); off += (size_t)NB * CAPB * sizeof(unsigned);
    off = (off + 255) & ~(size_t)255;
    unsigned short* yb = (unsigned short*)(w + off); off += (size_t)N * 64 * sizeof(unsigned short);

    if (ws_size >= off && NB <= MAXNB && N <= 65536) {   // c must fit 16 bits
        zero_kernel<<<32, 256, 0, stream>>>(cursor, NB * 16 + 1);  // cursors + spillcnt
        int splitB = 256;                            // 3125-edge chunks (TLP lever)
        int fcB = (N + 15) / 16;                     // 16 rows/block
        fc_split<<<splitB + fcB, 256, 0, stream>>>(x, Wfc, yb, N, eidx, buckets,
                                                   cursor, spillcnt, spill, E, NB, splitB);
        gatherz2<<<NB, 512, 0, stream>>>(buckets, cursor, (const uint2*)yb,
                                         (float4*)z, N, spillcnt, spill);
    } else {
        float* y = (float*)d_ws;
        hipMemsetAsync(d_out, 0, (size_t)out_size * sizeof(float), stream);
        fc_kernel<<<(N + 3) / 4, 256, 0, stream>>>(x, Wfc, y, N);
        scatter_kernel<<<4096, 256, 0, stream>>>(eidx, y, z, E);
    }
}

// Round 23
// 59.298 us; speedup vs baseline: 1.0634x; 1.0634x over previous
//
#include <hip/hip_runtime.h>
#include <hip/hip_bf16.h>

// z = segment_sum( (x @ W_fc^T)[col], row )  -- alpha==1 (softmax over singleton dim)
// Round 23: revert splitB to 128 (256 regressed: amplification+contention beat
// TLP). NEW: union the branch LDS (split: hist+bases 8KB | fc: sW+sX 21.5KB)
// into one smem buffer -> LDS 29.7KB -> 21.5KB, 5 -> 7 blocks/CU.
// Pipeline: zero -> fc||split -> gatherz2

#define BSHIFT 6
#define BNODES 64          // nodes per bucket
#define CAPB 2048          // u32 entries per bucket list (avg ~1024)
#define CAP 48             // slots per node (P(deg>48 | Poisson(16)) ~ 1e-11)
#define OVFCAP 128         // in-LDS overflow list (never used in practice)
#define SPILLCAP 65536
#define MAXNB 1024

__device__ inline unsigned short f2bf(float f) {
    __hip_bfloat16 h = __float2bfloat16(f);
    return *reinterpret_cast<unsigned short*>(&h);
}

// ---------- zero: cursors (stride-16) + spillcnt ----------
__global__ void zero_kernel(int* __restrict__ a, int n) {
    int i = blockIdx.x * blockDim.x + threadIdx.x;
    int s = gridDim.x * blockDim.x;
    for (; i < n; i += s) a[i] = 0;
}

// ---------- K1: blocks [0,splitB) split edges into packed bucket lists; rest fc ----------
// LDS union: split uses hist[MAXNB]+bases[MAXNB] (8KB); fc uses sW[64][68]+sX[16][64] (21.5KB)
#define SMEM_BYTES (64 * 68 * 4 + 16 * 64 * 4)   // 21504: fc branch is the max
__global__ __launch_bounds__(256) void fc_split(
        const float* __restrict__ x, const float* __restrict__ Wfc,
        unsigned short* __restrict__ y, int N,
        const int* __restrict__ eidx, unsigned* __restrict__ buckets,
        int* __restrict__ cursor, int* __restrict__ spillcnt, int* __restrict__ spill,
        int E, int NB, int splitB) {
    __shared__ __align__(16) char smem[SMEM_BYTES];
    if ((int)blockIdx.x < splitB) {
        int* hist  = (int*)smem;               // [MAXNB]
        int* bases = hist + MAXNB;             // [MAXNB]
        int chunk = (E + splitB - 1) / splitB;       // ~6250 -> 8 packed entries/run
        int e0 = (int)blockIdx.x * chunk;
        int e1 = e0 + chunk; if (e1 > E) e1 = E;
        for (int i = threadIdx.x; i < NB; i += 256) hist[i] = 0;
        __syncthreads();
        for (int e = e0 + threadIdx.x; e < e1; e += 256)
            atomicAdd(&hist[eidx[e] >> BSHIFT], 1);      // LDS hist, pass 1
        __syncthreads();
        for (int b = threadIdx.x; b < NB; b += 256) {
            int c = hist[b];
            bases[b] = c ? atomicAdd(&cursor[b * 16], c) : 0;  // 1 global atomic/bucket
            hist[b] = 0;                                 // reuse as rank counter
        }
        __syncthreads();
        for (int e = e0 + threadIdx.x; e < e1; e += 256) {   // pass 2 (L2-hot reread)
            int r = eidx[e];
            int c = eidx[E + e];
            int b = r >> BSHIFT;
            int pos = bases[b] + atomicAdd(&hist[b], 1);
            if (pos < CAPB) {
                buckets[(size_t)b * CAPB + pos] =
                    ((unsigned)(r & (BNODES - 1)) << 16) | (unsigned)c;
            } else {
                int q = atomicAdd(spillcnt, 1);
                if (q < SPILLCAP) { spill[2 * q] = r; spill[2 * q + 1] = c; }
            }
        }
    } else {
        // ---- fc: 16 rows/block (4/thread), bf16 out; float4 LDS reads ----
        float (*sW)[68] = (float (*)[68])smem;                    // 17408 B
        float (*sX)[64] = (float (*)[64])(smem + 64 * 68 * 4);    //  4096 B
        for (int i = threadIdx.x; i < 4096; i += 256) sW[i >> 6][i & 63] = Wfc[i];
        int row0 = ((int)blockIdx.x - splitB) << 4;
        for (int i = threadIdx.x; i < 1024; i += 256) {
            int r = i >> 6, k = i & 63, gr = row0 + r;
            sX[r][k] = (gr < N) ? x[(size_t)gr * 64 + k] : 0.f;
        }
        __syncthreads();
        int co = threadIdx.x & 63;
        int rq = threadIdx.x >> 6;
        const float4* wrow = reinterpret_cast<const float4*>(&sW[co][0]);
        const float4* xr0  = reinterpret_cast<const float4*>(&sX[4 * rq + 0][0]);
        const float4* xr1  = reinterpret_cast<const float4*>(&sX[4 * rq + 1][0]);
        const float4* xr2  = reinterpret_cast<const float4*>(&sX[4 * rq + 2][0]);
        const float4* xr3  = reinterpret_cast<const float4*>(&sX[4 * rq + 3][0]);
        float a0 = 0, a1 = 0, a2 = 0, a3 = 0;
#pragma unroll
        for (int m = 0; m < 16; ++m) {
            float4 w  = wrow[m];
            float4 v0 = xr0[m], v1 = xr1[m], v2 = xr2[m], v3 = xr3[m];
            a0 = fmaf(w.x, v0.x, fmaf(w.y, v0.y, fmaf(w.z, v0.z, fmaf(w.w, v0.w, a0))));
            a1 = fmaf(w.x, v1.x, fmaf(w.y, v1.y, fmaf(w.z, v1.z, fmaf(w.w, v1.w, a1))));
            a2 = fmaf(w.x, v2.x, fmaf(w.y, v2.y, fmaf(w.z, v2.z, fmaf(w.w, v2.w, a2))));
            a3 = fmaf(w.x, v3.x, fmaf(w.y, v3.y, fmaf(w.z, v3.z, fmaf(w.w, v3.w, a3))));
        }
        int g = row0 + 4 * rq;
        if (g + 3 < N) {
            y[(size_t)(g + 0) * 64 + co] = f2bf(a0);
            y[(size_t)(g + 1) * 64 + co] = f2bf(a1);
            y[(size_t)(g + 2) * 64 + co] = f2bf(a2);
            y[(size_t)(g + 3) * 64 + co] = f2bf(a3);
        } else {
            if (g + 0 < N) y[(size_t)(g + 0) * 64 + co] = f2bf(a0);
            if (g + 1 < N) y[(size_t)(g + 1) * 64 + co] = f2bf(a1);
            if (g + 2 < N) y[(size_t)(g + 2) * 64 + co] = f2bf(a2);
        }
    }
}

// ---------- K2: per-bucket block: LDS slot build (+spill ingest) + per-node ILP gather ----------
__device__ inline void acc_bf8(const uint2* yb, int c, int ch4,
                               float& r0, float& r1, float& r2, float& r3) {
    uint2 u = yb[(size_t)c * 16 + ch4];             // 8 B/lane, 128 B per 16-lane group
    r0 += __uint_as_float(u.x << 16);
    r1 += __uint_as_float(u.x & 0xffff0000u);
    r2 += __uint_as_float(u.y << 16);
    r3 += __uint_as_float(u.y & 0xffff0000u);
}
__global__ __launch_bounds__(512) void gatherz2(
        const unsigned* __restrict__ buckets, const int* __restrict__ cursor,
        const uint2* __restrict__ yb2, float4* __restrict__ z4, int N,
        const int* __restrict__ spillcnt, const int* __restrict__ spill) {
    __shared__ int cntL[BNODES];            // 256 B
    __shared__ int slotsL[BNODES * CAP];    // 12 KB
    __shared__ int ovfN[OVFCAP], ovfC[OVFCAP], ovfn_sh;
    int b  = (int)blockIdx.x;
    int lo = b << BSHIFT;
    for (int i = threadIdx.x; i < BNODES; i += 512) cntL[i] = 0;
    if (threadIdx.x == 0) ovfn_sh = 0;
    __syncthreads();
    int ecnt = cursor[b * 16]; if (ecnt > CAPB) ecnt = CAPB;
    const unsigned* blist = buckets + (size_t)b * CAPB;
    const uint2* blist2 = (const uint2*)blist;
    int nPairs = ecnt >> 1;
    for (int p = threadIdx.x; p < nPairs; p += 512) {   // coalesced 8B = 2 entries
        uint2 ee = blist2[p];
#pragma unroll
        for (int h = 0; h < 2; ++h) {
            unsigned e = h ? ee.y : ee.x;
            int n = (int)(e >> 16);
            int c = (int)(e & 0xffffu);
            int slot = atomicAdd(&cntL[n], 1);
            if (slot < CAP) slotsL[n * CAP + slot] = c;
            else { int q = atomicAdd(&ovfn_sh, 1);
                   if (q < OVFCAP) { ovfN[q] = n; ovfC[q] = c; } }
        }
    }
    if ((ecnt & 1) && threadIdx.x == 0) {               // tail entry
        unsigned e = blist[ecnt - 1];
        int n = (int)(e >> 16), c = (int)(e & 0xffffu);
        int slot = atomicAdd(&cntL[n], 1);
        if (slot < CAP) slotsL[n * CAP + slot] = c;
        else { int q = atomicAdd(&ovfn_sh, 1);
               if (q < OVFCAP) { ovfN[q] = n; ovfC[q] = c; } }
    }
    int sc = *spillcnt;                                  // fc_split CAPB overflow (0)
    if (sc > SPILLCAP) sc = SPILLCAP;
    for (int i = threadIdx.x; i < sc; i += 512) {
        int r = spill[2 * i];
        if ((r >> BSHIFT) == b) {
            int n = r & (BNODES - 1), c = spill[2 * i + 1];
            int slot = atomicAdd(&cntL[n], 1);
            if (slot < CAP) slotsL[n * CAP + slot] = c;
            else { int q = atomicAdd(&ovfn_sh, 1);
                   if (q < OVFCAP) { ovfN[q] = n; ovfC[q] = c; } }
        }
    }
    __syncthreads();
    int on = ovfn_sh; if (on > OVFCAP) on = OVFCAP;
    int lane = threadIdx.x & 63;
    int wv   = threadIdx.x >> 6;                       // 8 waves
    int sub  = lane >> 4;                              // edge slot within group-of-4
    int ch4  = lane & 15;                              // 4-channel group
    for (int n = wv; n < BNODES; n += 8) {
        int node = lo + n;
        if (node >= N) break;                          // monotonic per wave
        int deg = cntL[n]; if (deg > CAP) deg = CAP;
        const int* srow = &slotsL[n * CAP];
        float A0=0,A1=0,A2=0,A3=0, B0=0,B1=0,B2=0,B3=0,
              C0=0,C1=0,C2=0,C3=0, D0=0,D1=0,D2=0,D3=0;
        for (int j = 0; j < deg; j += 16) {
            int j0 = j + sub, j1 = j + 4 + sub, j2 = j + 8 + sub, j3 = j + 12 + sub;
            int c0 = (j0 < deg) ? srow[j0] : -1;       // LDS broadcast per 16-lane group
            int c1 = (j1 < deg) ? srow[j1] : -1;
            int c2 = (j2 < deg) ? srow[j2] : -1;
            int c3 = (j3 < deg) ? srow[j3] : -1;
            if (c0 >= 0) acc_bf8(yb2, c0, ch4, A0, A1, A2, A3);
            if (c1 >= 0) acc_bf8(yb2, c1, ch4, B0, B1, B2, B3);
            if (c2 >= 0) acc_bf8(yb2, c2, ch4, C0, C1, C2, C3);
            if (c3 >= 0) acc_bf8(yb2, c3, ch4, D0, D1, D2, D3);
        }
        for (int k = 0; k < on; ++k)                    // normally on == 0
            if (ovfN[k] == n && sub == 0)
                acc_bf8(yb2, ovfC[k], ch4, A0, A1, A2, A3);
        float r0 = (A0 + B0) + (C0 + D0);
        float r1 = (A1 + B1) + (C1 + D1);
        float r2 = (A2 + B2) + (C2 + D2);
        float r3 = (A3 + B3) + (C3 + D3);
        r0 += __shfl_xor(r0, 16, 64); r0 += __shfl_xor(r0, 32, 64);
        r1 += __shfl_xor(r1, 16, 64); r1 += __shfl_xor(r1, 32, 64);
        r2 += __shfl_xor(r2, 16, 64); r2 += __shfl_xor(r2, 32, 64);
        r3 += __shfl_xor(r3, 16, 64); r3 += __shfl_xor(r3, 32, 64);
        if (lane < 16)
            z4[(size_t)node * 16 + ch4] = make_float4(r0, r1, r2, r3);
    }
}

// ---------- fallback (ws too small or N too big): fc f32 + atomic scatter ----------
__global__ void fc_kernel(const float* __restrict__ x, const float* __restrict__ Wfc,
                          float* __restrict__ y, int N) {
    __shared__ float sW[64][65];
    __shared__ float sX[4][64];
    for (int i = threadIdx.x; i < 64 * 64; i += 256) sW[i >> 6][i & 63] = Wfc[i];
    int r = threadIdx.x >> 6, co = threadIdx.x & 63;
    int gRow = (blockIdx.x << 2) + r;
    sX[r][co] = (gRow < N) ? x[gRow * 64 + co] : 0.f;
    __syncthreads();
    if (gRow >= N) return;
    float acc = 0.f;
#pragma unroll
    for (int k = 0; k < 64; ++k) acc = fmaf(sX[r][k], sW[co][k], acc);
    y[gRow * 64 + co] = acc;
}
__global__ void scatter_kernel(const int* __restrict__ eidx, const float* __restrict__ y,
                               float* __restrict__ z, int E) {
    int lane = threadIdx.x & 63;
    int g  = (int)((blockIdx.x * blockDim.x + threadIdx.x) >> 6);
    int nG = (int)((gridDim.x * blockDim.x) >> 6);
    for (int e = g; e < E; e += nG) {
        int r = eidx[e], c = eidx[E + e];
        atomicAdd(&z[r * 64 + lane], y[c * 64 + lane]);
    }
}

extern "C" void kernel_launch(void* const* d_in, const int* in_sizes, int n_in,
                              void* d_out, int out_size, void* d_ws, size_t ws_size,
                              hipStream_t stream) {
    const float* x    = (const float*)d_in[0];
    const int*   eidx = (const int*)d_in[1];
    const float* Wfc  = (const float*)d_in[3];   // d_in[2,4,5] unused (alpha==1)
    float*       z    = (float*)d_out;

    int N = in_sizes[0] / 64;
    int E = in_sizes[1] / 2;
    int NB = (N + BNODES - 1) >> BSHIFT;         // 64-node buckets

    // workspace: cursor[NB*16] | spillcnt | spill | buckets(u32) | yb
    char* w = (char*)d_ws;
    size_t off = 0;
    int* cursor   = (int*)(w + off); off += (size_t)NB * 16 * sizeof(int);
    int* spillcnt = (int*)(w + off); off += sizeof(int);
    off = (off + 255) & ~(size_t)255;
    int* spill    = (int*)(w + off); off += (size_t)2 * SPILLCAP * sizeof(int);
    off = (off + 255) & ~(size_t)255;
    unsigned* buckets = (unsigned*)(w + off); off += (size_t)NB * CAPB * sizeof(unsigned);
    off = (off + 255) & ~(size_t)255;
    unsigned short* yb = (unsigned short*)(w + off); off += (size_t)N * 64 * sizeof(unsigned short);

    if (ws_size >= off && NB <= MAXNB && N <= 65536) {   // c must fit 16 bits
        zero_kernel<<<32, 256, 0, stream>>>(cursor, NB * 16 + 1);  // cursors + spillcnt
        int splitB = 128;                            // proven optimum (r21)
        int fcB = (N + 15) / 16;                     // 16 rows/block
        fc_split<<<splitB + fcB, 256, 0, stream>>>(x, Wfc, yb, N, eidx, buckets,
                                                   cursor, spillcnt, spill, E, NB, splitB);
        gatherz2<<<NB, 512, 0, stream>>>(buckets, cursor, (const uint2*)yb,
                                         (float4*)z, N, spillcnt, spill);
    } else {
        float* y = (float*)d_ws;
        hipMemsetAsync(d_out, 0, (size_t)out_size * sizeof(float), stream);
        fc_kernel<<<(N + 3) / 4, 256, 0, stream>>>(x, Wfc, y, N);
        scatter_kernel<<<4096, 256, 0, stream>>>(eidx, y, z, E);
    }
}

// Round 24
// 56.836 us; speedup vs baseline: 1.1094x; 1.0433x over previous
//
#include <hip/hip_runtime.h>
#include <hip/hip_bf16.h>

// z = segment_sum( (x @ W_fc^T)[col], row )  -- alpha==1 (softmax over singleton dim)
// Round 24: 4x manual unroll of both split passes (batch 4 loads -> 4 LDS
// atomics -> 4 stores; MLP 1->4 per thread). Split's 27us was a serial
// per-edge dependent chain. Everything else identical to r23 (59.3us).
// Pipeline: zero -> fc||split -> gatherz2

#define BSHIFT 6
#define BNODES 64          // nodes per bucket
#define CAPB 2048          // u32 entries per bucket list (avg ~1024)
#define CAP 48             // slots per node (P(deg>48 | Poisson(16)) ~ 1e-11)
#define OVFCAP 128         // in-LDS overflow list (never used in practice)
#define SPILLCAP 65536
#define MAXNB 1024

__device__ inline unsigned short f2bf(float f) {
    __hip_bfloat16 h = __float2bfloat16(f);
    return *reinterpret_cast<unsigned short*>(&h);
}

// ---------- zero: cursors (stride-16) + spillcnt ----------
__global__ void zero_kernel(int* __restrict__ a, int n) {
    int i = blockIdx.x * blockDim.x + threadIdx.x;
    int s = gridDim.x * blockDim.x;
    for (; i < n; i += s) a[i] = 0;
}

// ---------- K1: blocks [0,splitB) split edges into packed bucket lists; rest fc ----------
#define SMEM_BYTES (64 * 68 * 4 + 16 * 64 * 4)   // 21504: fc branch is the max
__global__ __launch_bounds__(256) void fc_split(
        const float* __restrict__ x, const float* __restrict__ Wfc,
        unsigned short* __restrict__ y, int N,
        const int* __restrict__ eidx, unsigned* __restrict__ buckets,
        int* __restrict__ cursor, int* __restrict__ spillcnt, int* __restrict__ spill,
        int E, int NB, int splitB) {
    __shared__ __align__(16) char smem[SMEM_BYTES];
    if ((int)blockIdx.x < splitB) {
        int* hist  = (int*)smem;               // [MAXNB]
        int* bases = hist + MAXNB;             // [MAXNB]
        int chunk = (E + splitB - 1) / splitB;       // ~6250 -> 8 packed entries/run
        int e0 = (int)blockIdx.x * chunk;
        int e1 = e0 + chunk; if (e1 > E) e1 = E;
        for (int i = threadIdx.x; i < NB; i += 256) hist[i] = 0;
        __syncthreads();
        // ---- pass 1: histogram, 4-deep MLP ----
        int e = e0 + threadIdx.x;
        for (; e + 768 < e1; e += 1024) {
            int r0 = eidx[e], r1 = eidx[e + 256], r2 = eidx[e + 512], r3 = eidx[e + 768];
            atomicAdd(&hist[r0 >> BSHIFT], 1);
            atomicAdd(&hist[r1 >> BSHIFT], 1);
            atomicAdd(&hist[r2 >> BSHIFT], 1);
            atomicAdd(&hist[r3 >> BSHIFT], 1);
        }
        for (; e < e1; e += 256) atomicAdd(&hist[eidx[e] >> BSHIFT], 1);
        __syncthreads();
        for (int b = threadIdx.x; b < NB; b += 256) {
            int c = hist[b];
            bases[b] = c ? atomicAdd(&cursor[b * 16], c) : 0;  // 1 global atomic/bucket
            hist[b] = 0;                                 // reuse as rank counter
        }
        __syncthreads();
        // ---- pass 2: scatter to packed bucket lists, 4-deep MLP ----
        e = e0 + threadIdx.x;
        for (; e + 768 < e1; e += 1024) {
            int r0 = eidx[e],       r1 = eidx[e + 256],
                r2 = eidx[e + 512], r3 = eidx[e + 768];
            int c0 = eidx[E + e],       c1 = eidx[E + e + 256],
                c2 = eidx[E + e + 512], c3 = eidx[E + e + 768];
            int b0 = r0 >> BSHIFT, b1 = r1 >> BSHIFT,
                b2 = r2 >> BSHIFT, b3 = r3 >> BSHIFT;
            int p0 = bases[b0] + atomicAdd(&hist[b0], 1);
            int p1 = bases[b1] + atomicAdd(&hist[b1], 1);
            int p2 = bases[b2] + atomicAdd(&hist[b2], 1);
            int p3 = bases[b3] + atomicAdd(&hist[b3], 1);
            if (p0 < CAPB) buckets[(size_t)b0 * CAPB + p0] =
                ((unsigned)(r0 & (BNODES - 1)) << 16) | (unsigned)c0;
            else { int q = atomicAdd(spillcnt, 1);
                   if (q < SPILLCAP) { spill[2 * q] = r0; spill[2 * q + 1] = c0; } }
            if (p1 < CAPB) buckets[(size_t)b1 * CAPB + p1] =
                ((unsigned)(r1 & (BNODES - 1)) << 16) | (unsigned)c1;
            else { int q = atomicAdd(spillcnt, 1);
                   if (q < SPILLCAP) { spill[2 * q] = r1; spill[2 * q + 1] = c1; } }
            if (p2 < CAPB) buckets[(size_t)b2 * CAPB + p2] =
                ((unsigned)(r2 & (BNODES - 1)) << 16) | (unsigned)c2;
            else { int q = atomicAdd(spillcnt, 1);
                   if (q < SPILLCAP) { spill[2 * q] = r2; spill[2 * q + 1] = c2; } }
            if (p3 < CAPB) buckets[(size_t)b3 * CAPB + p3] =
                ((unsigned)(r3 & (BNODES - 1)) << 16) | (unsigned)c3;
            else { int q = atomicAdd(spillcnt, 1);
                   if (q < SPILLCAP) { spill[2 * q] = r3; spill[2 * q + 1] = c3; } }
        }
        for (; e < e1; e += 256) {
            int r = eidx[e];
            int c = eidx[E + e];
            int b = r >> BSHIFT;
            int pos = bases[b] + atomicAdd(&hist[b], 1);
            if (pos < CAPB) {
                buckets[(size_t)b * CAPB + pos] =
                    ((unsigned)(r & (BNODES - 1)) << 16) | (unsigned)c;
            } else {
                int q = atomicAdd(spillcnt, 1);
                if (q < SPILLCAP) { spill[2 * q] = r; spill[2 * q + 1] = c; }
            }
        }
    } else {
        // ---- fc: 16 rows/block (4/thread), bf16 out; float4 LDS reads ----
        float (*sW)[68] = (float (*)[68])smem;                    // 17408 B
        float (*sX)[64] = (float (*)[64])(smem + 64 * 68 * 4);    //  4096 B
        for (int i = threadIdx.x; i < 4096; i += 256) sW[i >> 6][i & 63] = Wfc[i];
        int row0 = ((int)blockIdx.x - splitB) << 4;
        for (int i = threadIdx.x; i < 1024; i += 256) {
            int r = i >> 6, k = i & 63, gr = row0 + r;
            sX[r][k] = (gr < N) ? x[(size_t)gr * 64 + k] : 0.f;
        }
        __syncthreads();
        int co = threadIdx.x & 63;
        int rq = threadIdx.x >> 6;
        const float4* wrow = reinterpret_cast<const float4*>(&sW[co][0]);
        const float4* xr0  = reinterpret_cast<const float4*>(&sX[4 * rq + 0][0]);
        const float4* xr1  = reinterpret_cast<const float4*>(&sX[4 * rq + 1][0]);
        const float4* xr2  = reinterpret_cast<const float4*>(&sX[4 * rq + 2][0]);
        const float4* xr3  = reinterpret_cast<const float4*>(&sX[4 * rq + 3][0]);
        float a0 = 0, a1 = 0, a2 = 0, a3 = 0;
#pragma unroll
        for (int m = 0; m < 16; ++m) {
            float4 w  = wrow[m];
            float4 v0 = xr0[m], v1 = xr1[m], v2 = xr2[m], v3 = xr3[m];
            a0 = fmaf(w.x, v0.x, fmaf(w.y, v0.y, fmaf(w.z, v0.z, fmaf(w.w, v0.w, a0))));
            a1 = fmaf(w.x, v1.x, fmaf(w.y, v1.y, fmaf(w.z, v1.z, fmaf(w.w, v1.w, a1))));
            a2 = fmaf(w.x, v2.x, fmaf(w.y, v2.y, fmaf(w.z, v2.z, fmaf(w.w, v2.w, a2))));
            a3 = fmaf(w.x, v3.x, fmaf(w.y, v3.y, fmaf(w.z, v3.z, fmaf(w.w, v3.w, a3))));
        }
        int g = row0 + 4 * rq;
        if (g + 3 < N) {
            y[(size_t)(g + 0) * 64 + co] = f2bf(a0);
            y[(size_t)(g + 1) * 64 + co] = f2bf(a1);
            y[(size_t)(g + 2) * 64 + co] = f2bf(a2);
            y[(size_t)(g + 3) * 64 + co] = f2bf(a3);
        } else {
            if (g + 0 < N) y[(size_t)(g + 0) * 64 + co] = f2bf(a0);
            if (g + 1 < N) y[(size_t)(g + 1) * 64 + co] = f2bf(a1);
            if (g + 2 < N) y[(size_t)(g + 2) * 64 + co] = f2bf(a2);
        }
    }
}

// ---------- K2: per-bucket block: LDS slot build (+spill ingest) + per-node ILP gather ----------
__device__ inline void acc_bf8(const uint2* yb, int c, int ch4,
                               float& r0, float& r1, float& r2, float& r3) {
    uint2 u = yb[(size_t)c * 16 + ch4];             // 8 B/lane, 128 B per 16-lane group
    r0 += __uint_as_float(u.x << 16);
    r1 += __uint_as_float(u.x & 0xffff0000u);
    r2 += __uint_as_float(u.y << 16);
    r3 += __uint_as_float(u.y & 0xffff0000u);
}
__global__ __launch_bounds__(512) void gatherz2(
        const unsigned* __restrict__ buckets, const int* __restrict__ cursor,
        const uint2* __restrict__ yb2, float4* __restrict__ z4, int N,
        const int* __restrict__ spillcnt, const int* __restrict__ spill) {
    __shared__ int cntL[BNODES];            // 256 B
    __shared__ int slotsL[BNODES * CAP];    // 12 KB
    __shared__ int ovfN[OVFCAP], ovfC[OVFCAP], ovfn_sh;
    int b  = (int)blockIdx.x;
    int lo = b << BSHIFT;
    for (int i = threadIdx.x; i < BNODES; i += 512) cntL[i] = 0;
    if (threadIdx.x == 0) ovfn_sh = 0;
    __syncthreads();
    int ecnt = cursor[b * 16]; if (ecnt > CAPB) ecnt = CAPB;
    const unsigned* blist = buckets + (size_t)b * CAPB;
    const uint2* blist2 = (const uint2*)blist;
    int nPairs = ecnt >> 1;
    for (int p = threadIdx.x; p < nPairs; p += 512) {   // coalesced 8B = 2 entries
        uint2 ee = blist2[p];
#pragma unroll
        for (int h = 0; h < 2; ++h) {
            unsigned e = h ? ee.y : ee.x;
            int n = (int)(e >> 16);
            int c = (int)(e & 0xffffu);
            int slot = atomicAdd(&cntL[n], 1);
            if (slot < CAP) slotsL[n * CAP + slot] = c;
            else { int q = atomicAdd(&ovfn_sh, 1);
                   if (q < OVFCAP) { ovfN[q] = n; ovfC[q] = c; } }
        }
    }
    if ((ecnt & 1) && threadIdx.x == 0) {               // tail entry
        unsigned e = blist[ecnt - 1];
        int n = (int)(e >> 16), c = (int)(e & 0xffffu);
        int slot = atomicAdd(&cntL[n], 1);
        if (slot < CAP) slotsL[n * CAP + slot] = c;
        else { int q = atomicAdd(&ovfn_sh, 1);
               if (q < OVFCAP) { ovfN[q] = n; ovfC[q] = c; } }
    }
    int sc = *spillcnt;                                  // fc_split CAPB overflow (0)
    if (sc > SPILLCAP) sc = SPILLCAP;
    for (int i = threadIdx.x; i < sc; i += 512) {
        int r = spill[2 * i];
        if ((r >> BSHIFT) == b) {
            int n = r & (BNODES - 1), c = spill[2 * i + 1];
            int slot = atomicAdd(&cntL[n], 1);
            if (slot < CAP) slotsL[n * CAP + slot] = c;
            else { int q = atomicAdd(&ovfn_sh, 1);
                   if (q < OVFCAP) { ovfN[q] = n; ovfC[q] = c; } }
        }
    }
    __syncthreads();
    int on = ovfn_sh; if (on > OVFCAP) on = OVFCAP;
    int lane = threadIdx.x & 63;
    int wv   = threadIdx.x >> 6;                       // 8 waves
    int sub  = lane >> 4;                              // edge slot within group-of-4
    int ch4  = lane & 15;                              // 4-channel group
    for (int n = wv; n < BNODES; n += 8) {
        int node = lo + n;
        if (node >= N) break;                          // monotonic per wave
        int deg = cntL[n]; if (deg > CAP) deg = CAP;
        const int* srow = &slotsL[n * CAP];
        float A0=0,A1=0,A2=0,A3=0, B0=0,B1=0,B2=0,B3=0,
              C0=0,C1=0,C2=0,C3=0, D0=0,D1=0,D2=0,D3=0;
        for (int j = 0; j < deg; j += 16) {
            int j0 = j + sub, j1 = j + 4 + sub, j2 = j + 8 + sub, j3 = j + 12 + sub;
            int c0 = (j0 < deg) ? srow[j0] : -1;       // LDS broadcast per 16-lane group
            int c1 = (j1 < deg) ? srow[j1] : -1;
            int c2 = (j2 < deg) ? srow[j2] : -1;
            int c3 = (j3 < deg) ? srow[j3] : -1;
            if (c0 >= 0) acc_bf8(yb2, c0, ch4, A0, A1, A2, A3);
            if (c1 >= 0) acc_bf8(yb2, c1, ch4, B0, B1, B2, B3);
            if (c2 >= 0) acc_bf8(yb2, c2, ch4, C0, C1, C2, C3);
            if (c3 >= 0) acc_bf8(yb2, c3, ch4, D0, D1, D2, D3);
        }
        for (int k = 0; k < on; ++k)                    // normally on == 0
            if (ovfN[k] == n && sub == 0)
                acc_bf8(yb2, ovfC[k], ch4, A0, A1, A2, A3);
        float r0 = (A0 + B0) + (C0 + D0);
        float r1 = (A1 + B1) + (C1 + D1);
        float r2 = (A2 + B2) + (C2 + D2);
        float r3 = (A3 + B3) + (C3 + D3);
        r0 += __shfl_xor(r0, 16, 64); r0 += __shfl_xor(r0, 32, 64);
        r1 += __shfl_xor(r1, 16, 64); r1 += __shfl_xor(r1, 32, 64);
        r2 += __shfl_xor(r2, 16, 64); r2 += __shfl_xor(r2, 32, 64);
        r3 += __shfl_xor(r3, 16, 64); r3 += __shfl_xor(r3, 32, 64);
        if (lane < 16)
            z4[(size_t)node * 16 + ch4] = make_float4(r0, r1, r2, r3);
    }
}

// ---------- fallback (ws too small or N too big): fc f32 + atomic scatter ----------
__global__ void fc_kernel(const float* __restrict__ x, const float* __restrict__ Wfc,
                          float* __restrict__ y, int N) {
    __shared__ float sW[64][65];
    __shared__ float sX[4][64];
    for (int i = threadIdx.x; i < 64 * 64; i += 256) sW[i >> 6][i & 63] = Wfc[i];
    int r = threadIdx.x >> 6, co = threadIdx.x & 63;
    int gRow = (blockIdx.x << 2) + r;
    sX[r][co] = (gRow < N) ? x[gRow * 64 + co] : 0.f;
    __syncthreads();
    if (gRow >= N) return;
    float acc = 0.f;
#pragma unroll
    for (int k = 0; k < 64; ++k) acc = fmaf(sX[r][k], sW[co][k], acc);
    y[gRow * 64 + co] = acc;
}
__global__ void scatter_kernel(const int* __restrict__ eidx, const float* __restrict__ y,
                               float* __restrict__ z, int E) {
    int lane = threadIdx.x & 63;
    int g  = (int)((blockIdx.x * blockDim.x + threadIdx.x) >> 6);
    int nG = (int)((gridDim.x * blockDim.x) >> 6);
    for (int e = g; e < E; e += nG) {
        int r = eidx[e], c = eidx[E + e];
        atomicAdd(&z[r * 64 + lane], y[c * 64 + lane]);
    }
}

extern "C" void kernel_launch(void* const* d_in, const int* in_sizes, int n_in,
                              void* d_out, int out_size, void* d_ws, size_t ws_size,
                              hipStream_t stream) {
    const float* x    = (const float*)d_in[0];
    const int*   eidx = (const int*)d_in[1];
    const float* Wfc  = (const float*)d_in[3];   // d_in[2,4,5] unused (alpha==1)
    float*       z    = (float*)d_out;

    int N = in_sizes[0] / 64;
    int E = in_sizes[1] / 2;
    int NB = (N + BNODES - 1) >> BSHIFT;         // 64-node buckets

    // workspace: cursor[NB*16] | spillcnt | spill | buckets(u32) | yb
    char* w = (char*)d_ws;
    size_t off = 0;
    int* cursor   = (int*)(w + off); off += (size_t)NB * 16 * sizeof(int);
    int* spillcnt = (int*)(w + off); off += sizeof(int);
    off = (off + 255) & ~(size_t)255;
    int* spill    = (int*)(w + off); off += (size_t)2 * SPILLCAP * sizeof(int);
    off = (off + 255) & ~(size_t)255;
    unsigned* buckets = (unsigned*)(w + off); off += (size_t)NB * CAPB * sizeof(unsigned);
    off = (off + 255) & ~(size_t)255;
    unsigned short* yb = (unsigned short*)(w + off); off += (size_t)N * 64 * sizeof(unsigned short);

    if (ws_size >= off && NB <= MAXNB && N <= 65536) {   // c must fit 16 bits
        zero_kernel<<<32, 256, 0, stream>>>(cursor, NB * 16 + 1);  // cursors + spillcnt
        int splitB = 128;                            // proven optimum (r21)
        int fcB = (N + 15) / 16;                     // 16 rows/block
        fc_split<<<splitB + fcB, 256, 0, stream>>>(x, Wfc, yb, N, eidx, buckets,
                                                   cursor, spillcnt, spill, E, NB, splitB);
        gatherz2<<<NB, 512, 0, stream>>>(buckets, cursor, (const uint2*)yb,
                                         (float4*)z, N, spillcnt, spill);
    } else {
        float* y = (float*)d_ws;
        hipMemsetAsync(d_out, 0, (size_t)out_size * sizeof(float), stream);
        fc_kernel<<<(N + 3) / 4, 256, 0, stream>>>(x, Wfc, y, N);
        scatter_kernel<<<4096, 256, 0, stream>>>(eidx, y, z, E);
    }
}

// Round 25
// 56.098 us; speedup vs baseline: 1.1240x; 1.0131x over previous
//
#include <hip/hip_runtime.h>
#include <hip/hip_bf16.h>

// z = segment_sum( (x @ W_fc^T)[col], row )  -- alpha==1 (softmax over singleton dim)
// Round 25: vectorized index loads. Split pass1/pass2 read r (and c) as int4
// (16B/lane, 4x fewer load issues feeding the 4-deep atomic/store unroll);
// gatherz2 build reads 4 packed entries per uint4. Scalar head/tail for
// alignment; E%4==0 host-guarded. Everything else identical to r24 (56.8us).
// Pipeline: zero -> fc||split -> gatherz2

#define BSHIFT 6
#define BNODES 64          // nodes per bucket
#define CAPB 2048          // u32 entries per bucket list (avg ~1024)
#define CAP 48             // slots per node (P(deg>48 | Poisson(16)) ~ 1e-11)
#define OVFCAP 128         // in-LDS overflow list (never used in practice)
#define SPILLCAP 65536
#define MAXNB 1024

__device__ inline unsigned short f2bf(float f) {
    __hip_bfloat16 h = __float2bfloat16(f);
    return *reinterpret_cast<unsigned short*>(&h);
}

// ---------- zero: cursors (stride-16) + spillcnt ----------
__global__ void zero_kernel(int* __restrict__ a, int n) {
    int i = blockIdx.x * blockDim.x + threadIdx.x;
    int s = gridDim.x * blockDim.x;
    for (; i < n; i += s) a[i] = 0;
}

// ---------- K1: blocks [0,splitB) split edges into packed bucket lists; rest fc ----------
#define SMEM_BYTES (64 * 68 * 4 + 16 * 64 * 4)   // 21504: fc branch is the max
__global__ __launch_bounds__(256) void fc_split(
        const float* __restrict__ x, const float* __restrict__ Wfc,
        unsigned short* __restrict__ y, int N,
        const int* __restrict__ eidx, unsigned* __restrict__ buckets,
        int* __restrict__ cursor, int* __restrict__ spillcnt, int* __restrict__ spill,
        int E, int NB, int splitB) {
    __shared__ __align__(16) char smem[SMEM_BYTES];
    if ((int)blockIdx.x < splitB) {
        int* hist  = (int*)smem;               // [MAXNB]
        int* bases = hist + MAXNB;             // [MAXNB]
        int chunk = (E + splitB - 1) / splitB;       // ~6250 -> 8 packed entries/run
        int e0 = (int)blockIdx.x * chunk;
        int e1 = e0 + chunk; if (e1 > E) e1 = E;
        int ea = (e0 + 3) & ~3;                      // int4-aligned body
        int eb = e1 & ~3;
        for (int i = threadIdx.x; i < NB; i += 256) hist[i] = 0;
        __syncthreads();
        // ---- pass 1: histogram; int4 loads, 4 atomics per iter ----
        if ((int)threadIdx.x < ea - e0) atomicAdd(&hist[eidx[e0 + threadIdx.x] >> BSHIFT], 1);
        {
            const int4* r4p = (const int4*)eidx;
            for (int i = (ea >> 2) + threadIdx.x; i < (eb >> 2); i += 256) {
                int4 v = r4p[i];                     // coalesced 16B/lane
                atomicAdd(&hist[v.x >> BSHIFT], 1);
                atomicAdd(&hist[v.y >> BSHIFT], 1);
                atomicAdd(&hist[v.z >> BSHIFT], 1);
                atomicAdd(&hist[v.w >> BSHIFT], 1);
            }
        }
        if ((int)threadIdx.x < e1 - eb) atomicAdd(&hist[eidx[eb + threadIdx.x] >> BSHIFT], 1);
        __syncthreads();
        for (int b = threadIdx.x; b < NB; b += 256) {
            int c = hist[b];
            bases[b] = c ? atomicAdd(&cursor[b * 16], c) : 0;  // 1 global atomic/bucket
            hist[b] = 0;                                 // reuse as rank counter
        }
        __syncthreads();
        // ---- pass 2: scatter to packed bucket lists; int4 loads ----
        const int4* r4p = (const int4*)eidx;
        const int4* c4p = (const int4*)(eidx + E);   // E%4==0 (host-guarded)
        auto emit = [&](int r, int c) {
            int b = r >> BSHIFT;
            int pos = bases[b] + atomicAdd(&hist[b], 1);
            if (pos < CAPB) {
                buckets[(size_t)b * CAPB + pos] =
                    ((unsigned)(r & (BNODES - 1)) << 16) | (unsigned)c;
            } else {
                int q = atomicAdd(spillcnt, 1);
                if (q < SPILLCAP) { spill[2 * q] = r; spill[2 * q + 1] = c; }
            }
        };
        if ((int)threadIdx.x < ea - e0) {
            int e = e0 + threadIdx.x;
            emit(eidx[e], eidx[E + e]);
        }
        for (int i = (ea >> 2) + threadIdx.x; i < (eb >> 2); i += 256) {
            int4 rv = r4p[i];
            int4 cv = c4p[i];
            emit(rv.x, cv.x);
            emit(rv.y, cv.y);
            emit(rv.z, cv.z);
            emit(rv.w, cv.w);
        }
        if ((int)threadIdx.x < e1 - eb) {
            int e = eb + threadIdx.x;
            emit(eidx[e], eidx[E + e]);
        }
    } else {
        // ---- fc: 16 rows/block (4/thread), bf16 out; float4 LDS reads ----
        float (*sW)[68] = (float (*)[68])smem;                    // 17408 B
        float (*sX)[64] = (float (*)[64])(smem + 64 * 68 * 4);    //  4096 B
        for (int i = threadIdx.x; i < 4096; i += 256) sW[i >> 6][i & 63] = Wfc[i];
        int row0 = ((int)blockIdx.x - splitB) << 4;
        for (int i = threadIdx.x; i < 1024; i += 256) {
            int r = i >> 6, k = i & 63, gr = row0 + r;
            sX[r][k] = (gr < N) ? x[(size_t)gr * 64 + k] : 0.f;
        }
        __syncthreads();
        int co = threadIdx.x & 63;
        int rq = threadIdx.x >> 6;
        const float4* wrow = reinterpret_cast<const float4*>(&sW[co][0]);
        const float4* xr0  = reinterpret_cast<const float4*>(&sX[4 * rq + 0][0]);
        const float4* xr1  = reinterpret_cast<const float4*>(&sX[4 * rq + 1][0]);
        const float4* xr2  = reinterpret_cast<const float4*>(&sX[4 * rq + 2][0]);
        const float4* xr3  = reinterpret_cast<const float4*>(&sX[4 * rq + 3][0]);
        float a0 = 0, a1 = 0, a2 = 0, a3 = 0;
#pragma unroll
        for (int m = 0; m < 16; ++m) {
            float4 w  = wrow[m];
            float4 v0 = xr0[m], v1 = xr1[m], v2 = xr2[m], v3 = xr3[m];
            a0 = fmaf(w.x, v0.x, fmaf(w.y, v0.y, fmaf(w.z, v0.z, fmaf(w.w, v0.w, a0))));
            a1 = fmaf(w.x, v1.x, fmaf(w.y, v1.y, fmaf(w.z, v1.z, fmaf(w.w, v1.w, a1))));
            a2 = fmaf(w.x, v2.x, fmaf(w.y, v2.y, fmaf(w.z, v2.z, fmaf(w.w, v2.w, a2))));
            a3 = fmaf(w.x, v3.x, fmaf(w.y, v3.y, fmaf(w.z, v3.z, fmaf(w.w, v3.w, a3))));
        }
        int g = row0 + 4 * rq;
        if (g + 3 < N) {
            y[(size_t)(g + 0) * 64 + co] = f2bf(a0);
            y[(size_t)(g + 1) * 64 + co] = f2bf(a1);
            y[(size_t)(g + 2) * 64 + co] = f2bf(a2);
            y[(size_t)(g + 3) * 64 + co] = f2bf(a3);
        } else {
            if (g + 0 < N) y[(size_t)(g + 0) * 64 + co] = f2bf(a0);
            if (g + 1 < N) y[(size_t)(g + 1) * 64 + co] = f2bf(a1);
            if (g + 2 < N) y[(size_t)(g + 2) * 64 + co] = f2bf(a2);
        }
    }
}

// ---------- K2: per-bucket block: LDS slot build (+spill ingest) + per-node ILP gather ----------
__device__ inline void acc_bf8(const uint2* yb, int c, int ch4,
                               float& r0, float& r1, float& r2, float& r3) {
    uint2 u = yb[(size_t)c * 16 + ch4];             // 8 B/lane, 128 B per 16-lane group
    r0 += __uint_as_float(u.x << 16);
    r1 += __uint_as_float(u.x & 0xffff0000u);
    r2 += __uint_as_float(u.y << 16);
    r3 += __uint_as_float(u.y & 0xffff0000u);
}
__global__ __launch_bounds__(512) void gatherz2(
        const unsigned* __restrict__ buckets, const int* __restrict__ cursor,
        const uint2* __restrict__ yb2, float4* __restrict__ z4, int N,
        const int* __restrict__ spillcnt, const int* __restrict__ spill) {
    __shared__ int cntL[BNODES];            // 256 B
    __shared__ int slotsL[BNODES * CAP];    // 12 KB
    __shared__ int ovfN[OVFCAP], ovfC[OVFCAP], ovfn_sh;
    int b  = (int)blockIdx.x;
    int lo = b << BSHIFT;
    for (int i = threadIdx.x; i < BNODES; i += 512) cntL[i] = 0;
    if (threadIdx.x == 0) ovfn_sh = 0;
    __syncthreads();
    int ecnt = cursor[b * 16]; if (ecnt > CAPB) ecnt = CAPB;
    const unsigned* blist = buckets + (size_t)b * CAPB;
    auto ingest = [&](unsigned e) {
        int n = (int)(e >> 16);
        int c = (int)(e & 0xffffu);
        int slot = atomicAdd(&cntL[n], 1);
        if (slot < CAP) slotsL[n * CAP + slot] = c;
        else { int q = atomicAdd(&ovfn_sh, 1);
               if (q < OVFCAP) { ovfN[q] = n; ovfC[q] = c; } }
    };
    {
        const uint4* blist4 = (const uint4*)blist;       // bucket base 8KB-aligned
        int n4 = ecnt >> 2;
        for (int p = threadIdx.x; p < n4; p += 512) {    // 16B = 4 entries per load
            uint4 ee = blist4[p];
            ingest(ee.x); ingest(ee.y); ingest(ee.z); ingest(ee.w);
        }
        int base = n4 << 2;
        if ((int)threadIdx.x < ecnt - base) ingest(blist[base + threadIdx.x]);
    }
    int sc = *spillcnt;                                  // fc_split CAPB overflow (0)
    if (sc > SPILLCAP) sc = SPILLCAP;
    for (int i = threadIdx.x; i < sc; i += 512) {
        int r = spill[2 * i];
        if ((r >> BSHIFT) == b) {
            int n = r & (BNODES - 1), c = spill[2 * i + 1];
            int slot = atomicAdd(&cntL[n], 1);
            if (slot < CAP) slotsL[n * CAP + slot] = c;
            else { int q = atomicAdd(&ovfn_sh, 1);
                   if (q < OVFCAP) { ovfN[q] = n; ovfC[q] = c; } }
        }
    }
    __syncthreads();
    int on = ovfn_sh; if (on > OVFCAP) on = OVFCAP;
    int lane = threadIdx.x & 63;
    int wv   = threadIdx.x >> 6;                       // 8 waves
    int sub  = lane >> 4;                              // edge slot within group-of-4
    int ch4  = lane & 15;                              // 4-channel group
    for (int n = wv; n < BNODES; n += 8) {
        int node = lo + n;
        if (node >= N) break;                          // monotonic per wave
        int deg = cntL[n]; if (deg > CAP) deg = CAP;
        const int* srow = &slotsL[n * CAP];
        float A0=0,A1=0,A2=0,A3=0, B0=0,B1=0,B2=0,B3=0,
              C0=0,C1=0,C2=0,C3=0, D0=0,D1=0,D2=0,D3=0;
        for (int j = 0; j < deg; j += 16) {
            int j0 = j + sub, j1 = j + 4 + sub, j2 = j + 8 + sub, j3 = j + 12 + sub;
            int c0 = (j0 < deg) ? srow[j0] : -1;       // LDS broadcast per 16-lane group
            int c1 = (j1 < deg) ? srow[j1] : -1;
            int c2 = (j2 < deg) ? srow[j2] : -1;
            int c3 = (j3 < deg) ? srow[j3] : -1;
            if (c0 >= 0) acc_bf8(yb2, c0, ch4, A0, A1, A2, A3);
            if (c1 >= 0) acc_bf8(yb2, c1, ch4, B0, B1, B2, B3);
            if (c2 >= 0) acc_bf8(yb2, c2, ch4, C0, C1, C2, C3);
            if (c3 >= 0) acc_bf8(yb2, c3, ch4, D0, D1, D2, D3);
        }
        for (int k = 0; k < on; ++k)                    // normally on == 0
            if (ovfN[k] == n && sub == 0)
                acc_bf8(yb2, ovfC[k], ch4, A0, A1, A2, A3);
        float r0 = (A0 + B0) + (C0 + D0);
        float r1 = (A1 + B1) + (C1 + D1);
        float r2 = (A2 + B2) + (C2 + D2);
        float r3 = (A3 + B3) + (C3 + D3);
        r0 += __shfl_xor(r0, 16, 64); r0 += __shfl_xor(r0, 32, 64);
        r1 += __shfl_xor(r1, 16, 64); r1 += __shfl_xor(r1, 32, 64);
        r2 += __shfl_xor(r2, 16, 64); r2 += __shfl_xor(r2, 32, 64);
        r3 += __shfl_xor(r3, 16, 64); r3 += __shfl_xor(r3, 32, 64);
        if (lane < 16)
            z4[(size_t)node * 16 + ch4] = make_float4(r0, r1, r2, r3);
    }
}

// ---------- fallback (ws too small, N too big, or E%4!=0): fc f32 + atomic scatter ----------
__global__ void fc_kernel(const float* __restrict__ x, const float* __restrict__ Wfc,
                          float* __restrict__ y, int N) {
    __shared__ float sW[64][65];
    __shared__ float sX[4][64];
    for (int i = threadIdx.x; i < 64 * 64; i += 256) sW[i >> 6][i & 63] = Wfc[i];
    int r = threadIdx.x >> 6, co = threadIdx.x & 63;
    int gRow = (blockIdx.x << 2) + r;
    sX[r][co] = (gRow < N) ? x[gRow * 64 + co] : 0.f;
    __syncthreads();
    if (gRow >= N) return;
    float acc = 0.f;
#pragma unroll
    for (int k = 0; k < 64; ++k) acc = fmaf(sX[r][k], sW[co][k], acc);
    y[gRow * 64 + co] = acc;
}
__global__ void scatter_kernel(const int* __restrict__ eidx, const float* __restrict__ y,
                               float* __restrict__ z, int E) {
    int lane = threadIdx.x & 63;
    int g  = (int)((blockIdx.x * blockDim.x + threadIdx.x) >> 6);
    int nG = (int)((gridDim.x * blockDim.x) >> 6);
    for (int e = g; e < E; e += nG) {
        int r = eidx[e], c = eidx[E + e];
        atomicAdd(&z[r * 64 + lane], y[c * 64 + lane]);
    }
}

extern "C" void kernel_launch(void* const* d_in, const int* in_sizes, int n_in,
                              void* d_out, int out_size, void* d_ws, size_t ws_size,
                              hipStream_t stream) {
    const float* x    = (const float*)d_in[0];
    const int*   eidx = (const int*)d_in[1];
    const float* Wfc  = (const float*)d_in[3];   // d_in[2,4,5] unused (alpha==1)
    float*       z    = (float*)d_out;

    int N = in_sizes[0] / 64;
    int E = in_sizes[1] / 2;
    int NB = (N + BNODES - 1) >> BSHIFT;         // 64-node buckets

    // workspace: cursor[NB*16] | spillcnt | spill | buckets(u32) | yb
    char* w = (char*)d_ws;
    size_t off = 0;
    int* cursor   = (int*)(w + off); off += (size_t)NB * 16 * sizeof(int);
    int* spillcnt = (int*)(w + off); off += sizeof(int);
    off = (off + 255) & ~(size_t)255;
    int* spill    = (int*)(w + off); off += (size_t)2 * SPILLCAP * sizeof(int);
    off = (off + 255) & ~(size_t)255;
    unsigned* buckets = (unsigned*)(w + off); off += (size_t)NB * CAPB * sizeof(unsigned);
    off = (off + 255) & ~(size_t)255;
    unsigned short* yb = (unsigned short*)(w + off); off += (size_t)N * 64 * sizeof(unsigned short);

    if (ws_size >= off && NB <= MAXNB && N <= 65536 && (E & 3) == 0) {
        zero_kernel<<<32, 256, 0, stream>>>(cursor, NB * 16 + 1);  // cursors + spillcnt
        int splitB = 128;                            // proven optimum (r21)
        int fcB = (N + 15) / 16;                     // 16 rows/block
        fc_split<<<splitB + fcB, 256, 0, stream>>>(x, Wfc, yb, N, eidx, buckets,
                                                   cursor, spillcnt, spill, E, NB, splitB);
        gatherz2<<<NB, 512, 0, stream>>>(buckets, cursor, (const uint2*)yb,
                                         (float4*)z, N, spillcnt, spill);
    } else {
        float* y = (float*)d_ws;
        hipMemsetAsync(d_out, 0, (size_t)out_size * sizeof(float), stream);
        fc_kernel<<<(N + 3) / 4, 256, 0, stream>>>(x, Wfc, y, N);
        scatter_kernel<<<4096, 256, 0, stream>>>(eidx, y, z, E);
    }
}